// Round 10
// baseline (649.800 us; speedup 1.0000x reference)
//
#include <hip/hip_runtime.h>
#include <hip/hip_bf16.h>
#include <math.h>

// Problem constants (fixed by setup_inputs)
#define S_   64
#define H_   32
#define D_   128
#define KVH_ 8
#define G_   4
#define BS_  16
#define MB_  128
#define LMAX_ 2048

#define SCALE_ 0.08838834764831845f  // 1/sqrt(128)
#define MINIT_ -1.0e30f              // finite "neg-inf": corr=exp(m-mn) never NaN

// Wave-count-maximal flash-decode partial kernel.
// WG = 128 threads = 2 INDEPENDENT waves (no LDS, no barriers, no shared
// state): wave w owns work item (s, kvh, part = 2*blockIdx.x + w). The WG is
// only a packing container so that the per-CU workgroup-slot limit (~16)
// still admits 32 waves/CU. VGPR forced to 64 (8 waves/SIMD bucket).
// Per wave: 2 groups of 32 lanes; group owns PART/2 consecutive tokens
// (PART/32 pages). Inner loop per 4-token batch: burst 4 K rows -> dots ->
// butterfly reduce -> mask -> burst 4 V rows -> online-softmax update.
// Groups merged in-wave via width-64 shuffles; partial written directly.
template<int PART>
__global__ __launch_bounds__(128, 8)
void pa_partial(const float* __restrict__ q,
                const float* __restrict__ kc,
                const float* __restrict__ vc,
                const int* __restrict__ bt,
                const int* __restrict__ cl,
                float* __restrict__ ws)
{
    constexpr int MAXP = LMAX_ / PART;
    constexpr int PG   = PART / 32;      // pages per 32-lane group

    const int kvh = blockIdx.y;
    const int s   = blockIdx.z;
    const int wid = threadIdx.x >> 6;    // 0..1: independent wave
    const int part = blockIdx.x * 2 + wid;

    const int len = cl[s];
    const int t0  = part * PART;
    if (t0 >= len) return;               // per-wave exit (waves independent)

    const int lane = threadIdx.x & 63;
    const int sub  = lane >> 5;          // group 0..1 within wave
    const int l32  = lane & 31;          // float4 slice of D

    // Q fragments: this kvh's 4 GQA heads
    float4 qv[G_];
#pragma unroll
    for (int g = 0; g < G_; ++g)
        qv[g] = *(const float4*)(q + ((size_t)(s * H_ + kvh * G_ + g)) * D_ + l32 * 4);

    float  m[G_], l[G_];
    float4 acc[G_];
#pragma unroll
    for (int g = 0; g < G_; ++g) {
        m[g] = MINIT_; l[g] = 0.f;
        acc[g] = make_float4(0.f, 0.f, 0.f, 0.f);
    }

    const int* btr = bt + s * MB_;
    const size_t kvh_off = (size_t)kvh * (BS_ * D_);

    // Group sub's pages: page0 + sub*PG + pg
#pragma unroll
    for (int pg = 0; pg < PG; ++pg) {
        const int pidx  = (t0 >> 4) + sub * PG + pg;
        const int tpage = pidx * BS_;
        if (tpage >= len) continue;      // divergent between groups: exec-masked

        const int bid = btr[pidx];
        const float* kp = kc + (size_t)bid * (KVH_ * BS_ * D_) + kvh_off + l32 * 4;
        const float* vp = vc + (size_t)bid * (KVH_ * BS_ * D_) + kvh_off + l32 * 4;

#pragma unroll
        for (int b = 0; b < 4; ++b) {
            // Burst 4 K rows (any row of a valid page exists; scores masked).
            float4 k4[4];
#pragma unroll
            for (int i = 0; i < 4; ++i)
                k4[i] = *(const float4*)(kp + (size_t)(b * 4 + i) * D_);

            float sc[4][G_];
#pragma unroll
            for (int i = 0; i < 4; ++i)
#pragma unroll
                for (int g = 0; g < G_; ++g)
                    sc[i][g] = qv[g].x * k4[i].x + qv[g].y * k4[i].y +
                               qv[g].z * k4[i].z + qv[g].w * k4[i].w;

            // Butterfly reduce across the 32-lane group.
#pragma unroll
            for (int off = 16; off; off >>= 1)
#pragma unroll
                for (int i = 0; i < 4; ++i)
#pragma unroll
                    for (int g = 0; g < G_; ++g)
                        sc[i][g] += __shfl_xor(sc[i][g], off, 32);

            // Burst 4 V rows (independent of scores; overlaps the softmax).
            float4 v4[4];
#pragma unroll
            for (int i = 0; i < 4; ++i)
                v4[i] = *(const float4*)(vp + (size_t)(b * 4 + i) * D_);

            // Scale + mask tokens beyond len.
#pragma unroll
            for (int i = 0; i < 4; ++i) {
                const bool valid = (tpage + b * 4 + i) < len;
#pragma unroll
                for (int g = 0; g < G_; ++g)
                    sc[i][g] = valid ? sc[i][g] * SCALE_ : -INFINITY;
            }

            // Online-softmax update (m finite always; masked p -> 0).
#pragma unroll
            for (int g = 0; g < G_; ++g) {
                const float smax = fmaxf(fmaxf(sc[0][g], sc[1][g]),
                                         fmaxf(sc[2][g], sc[3][g]));
                const float mn   = fmaxf(m[g], smax);
                const float corr = __expf(m[g] - mn);
                const float p0 = __expf(sc[0][g] - mn);
                const float p1 = __expf(sc[1][g] - mn);
                const float p2 = __expf(sc[2][g] - mn);
                const float p3 = __expf(sc[3][g] - mn);
                l[g] = l[g] * corr + ((p0 + p1) + (p2 + p3));
                acc[g].x = acc[g].x * corr + p0 * v4[0].x + p1 * v4[1].x + p2 * v4[2].x + p3 * v4[3].x;
                acc[g].y = acc[g].y * corr + p0 * v4[0].y + p1 * v4[1].y + p2 * v4[2].y + p3 * v4[3].y;
                acc[g].z = acc[g].z * corr + p0 * v4[0].z + p1 * v4[1].z + p2 * v4[2].z + p3 * v4[3].z;
                acc[g].w = acc[g].w * corr + p0 * v4[0].w + p1 * v4[1].w + p2 * v4[2].w + p3 * v4[3].w;
                m[g] = mn;
            }
        }
    }

    // Merge the wave's two groups via width-64 shuffles (partner = lane^32),
    // then group-0 lanes write the partial record.
    // ws layout: [S_][KVH_][MAXP][G_][130] floats.
#pragma unroll
    for (int g = 0; g < G_; ++g) {
        const float mo = __shfl_xor(m[g], 32, 64);
        const float lo = __shfl_xor(l[g], 32, 64);
        const float ox = __shfl_xor(acc[g].x, 32, 64);
        const float oy = __shfl_xor(acc[g].y, 32, 64);
        const float oz = __shfl_xor(acc[g].z, 32, 64);
        const float ow = __shfl_xor(acc[g].w, 32, 64);
        const float M  = fmaxf(m[g], mo);
        const float w  = __expf(m[g] - M);
        const float wo = __expf(mo - M);
        const float L  = w * l[g] + wo * lo;
        float4 A;
        A.x = w * acc[g].x + wo * ox;
        A.y = w * acc[g].y + wo * oy;
        A.z = w * acc[g].z + wo * oz;
        A.w = w * acc[g].w + wo * ow;
        if (sub == 0) {
            float* pb = ws + (((size_t)(s * KVH_ + kvh) * MAXP + part) * G_ + g) * 130;
            if (l32 == 0) { pb[0] = M; pb[1] = L; }
            *(float4*)(pb + 2 + l32 * 4) = A;
        }
    }
}

// Combine kernel: one WG (128 threads) per (seq, head); reduce over partitions.
__global__ __launch_bounds__(128)
void pa_combine(const float* __restrict__ ws,
                const int* __restrict__ cl,
                float* __restrict__ out,
                int PART, int maxP)
{
    const int h = blockIdx.x;   // 0..31
    const int s = blockIdx.y;   // 0..63
    const int kvh = h >> 2;
    const int g   = h & 3;
    const int d   = threadIdx.x;

    const int len = cl[s];
    const int np  = (len + PART - 1) / PART;

    const float* base = ws + (((size_t)(s * KVH_ + kvh) * maxP) * G_ + g) * 130;

    float M = MINIT_;
    for (int p = 0; p < np; ++p) M = fmaxf(M, base[(size_t)p * (G_ * 130)]);

    float L = 0.f, val = 0.f;
    for (int p = 0; p < np; ++p) {
        const float* pb = base + (size_t)p * (G_ * 130);
        const float w = __expf(pb[0] - M);
        L   += w * pb[1];
        val += w * pb[2 + d];
    }
    out[((size_t)s * H_ + h) * D_ + d] = val / L;
}

extern "C" void kernel_launch(void* const* d_in, const int* in_sizes, int n_in,
                              void* d_out, int out_size, void* d_ws, size_t ws_size,
                              hipStream_t stream)
{
    const float* q  = (const float*)d_in[0];
    const float* kc = (const float*)d_in[1];
    const float* vc = (const float*)d_in[2];
    const int*   bt = (const int*)d_in[3];
    const int*   cl = (const int*)d_in[4];
    float* out = (float*)d_out;
    float* ws  = (float*)d_ws;

    // ws need: S*KVH*(LMAX/PART)*G*130*4 B. PART=64 -> 34 MB, 128 -> 17 MB,
    // 256 -> 8.5 MB. Smallest PART that fits (max parallelism/balance).
    auto need = [](int PARTv) {
        return (size_t)S_ * KVH_ * (LMAX_ / PARTv) * G_ * 130 * sizeof(float);
    };

    if (need(64) <= ws_size) {
        dim3 grid1((LMAX_ / 64) / 2, KVH_, S_);
        pa_partial<64><<<grid1, 128, 0, stream>>>(q, kc, vc, bt, cl, ws);
        dim3 grid2(H_, S_);
        pa_combine<<<grid2, 128, 0, stream>>>(ws, cl, out, 64, LMAX_ / 64);
    } else if (need(128) <= ws_size) {
        dim3 grid1((LMAX_ / 128) / 2, KVH_, S_);
        pa_partial<128><<<grid1, 128, 0, stream>>>(q, kc, vc, bt, cl, ws);
        dim3 grid2(H_, S_);
        pa_combine<<<grid2, 128, 0, stream>>>(ws, cl, out, 128, LMAX_ / 128);
    } else {
        dim3 grid1((LMAX_ / 256) / 2, KVH_, S_);
        pa_partial<256><<<grid1, 128, 0, stream>>>(q, kc, vc, bt, cl, ws);
        dim3 grid2(H_, S_);
        pa_combine<<<grid2, 128, 0, stream>>>(ws, cl, out, 256, LMAX_ / 256);
    }
}

// Round 11
// 251.212 us; speedup vs baseline: 2.5867x; 2.5867x over previous
//
#include <hip/hip_runtime.h>
#include <hip/hip_bf16.h>
#include <math.h>

// Problem constants (fixed by setup_inputs)
#define S_   64
#define H_   32
#define D_   128
#define KVH_ 8
#define G_   4
#define BS_  16
#define MB_  128
#define LMAX_ 2048
#define PART_ 128
#define MAXP_ (LMAX_ / PART_)   // 16
#define NPG_  (PART_ / BS_)     // 8 pages per work item

#define SCALE_ 0.08838834764831845f  // 1/sqrt(128)
#define MINIT_ -1.0e30f              // finite "neg-inf": corr=exp(m-mn) never NaN

typedef __attribute__((address_space(1))) const float gfloat;
typedef __attribute__((address_space(3))) float lfloat;

// Deep-DMA flash-decode partial kernel.
// One 64-lane wave per WG owns (seq, kv_head, 128-token partition = 8 pages).
// Page pipeline: issue 16x global_load_lds (16KB, zero VGPR) for page p+1,
// s_waitcnt vmcnt(16) (page p arrived, p+1 still in flight), compute page p
// from LDS. Wave-private LDS double buffer -> no barriers, no inter-wave
// coupling. 5 WGs/CU (32KB LDS each) keep 80KB/CU outstanding -> HBM-bound
// by Little's law even at 5 waves/CU.
// Compute: 2 groups of 32 lanes; group sub owns rows sub*8..sub*8+7 of the
// page as 2 batches of 4 tokens; lane owns a float4 slice of D; 4 GQA heads
// per group; groups merged at the end via width-64 shuffles.
__global__ __launch_bounds__(64)
void pa_partial(const float* __restrict__ q,
                const float* __restrict__ kc,
                const float* __restrict__ vc,
                const int* __restrict__ bt,
                const int* __restrict__ cl,
                float* __restrict__ ws)
{
    const int part = blockIdx.x;
    const int kvh  = blockIdx.y;
    const int s    = blockIdx.z;

    const int len = cl[s];
    const int t0  = part * PART_;
    if (t0 >= len) return;
    const int np = min(NPG_, ((len - t0) + BS_ - 1) >> 4);

    const int lane = threadIdx.x;   // 0..63
    const int sub  = lane >> 5;     // group 0..1
    const int l32  = lane & 31;     // float4 slice of D

    __shared__ float sbuf[2][2 * BS_ * D_];   // [buf][K 2048 floats | V 2048 floats] = 32 KB

    // Page block-ids up front, constant-indexed (no scratch, no per-page
    // dependent-load stall). t0>>4 <= 120, +8 <= 128 = MB_ -> always in-bounds.
    int bids[NPG_];
    {
        const int* btr = bt + s * MB_ + (t0 >> 4);
#pragma unroll
        for (int j = 0; j < NPG_; ++j) bids[j] = btr[j];
    }

    // Q fragments: this kvh's 4 GQA heads
    float4 qv[G_];
#pragma unroll
    for (int g = 0; g < G_; ++g)
        qv[g] = *(const float4*)(q + ((size_t)(s * H_ + kvh * G_ + g)) * D_ + l32 * 4);

    float  m[G_], l[G_];
    float4 acc[G_];
#pragma unroll
    for (int g = 0; g < G_; ++g) {
        m[g] = MINIT_; l[g] = 0.f;
        acc[g] = make_float4(0.f, 0.f, 0.f, 0.f);
    }

    const size_t kvh_off = (size_t)kvh * (BS_ * D_);

    // Issue the 16 DMA loads (8 K + 8 V chunks of 1KB) for a page.
    auto stage = [&](int bufi, int bid) {
        const float* kp = kc + (size_t)bid * (KVH_ * BS_ * D_) + kvh_off;
        const float* vp = vc + (size_t)bid * (KVH_ * BS_ * D_) + kvh_off;
        float* bK = &sbuf[bufi][0];
        float* bV = &sbuf[bufi][2048];
#pragma unroll
        for (int j = 0; j < 8; ++j) {
            __builtin_amdgcn_global_load_lds((gfloat*)(kp + j * 256 + lane * 4),
                                             (lfloat*)&bK[j * 256], 16, 0, 0);
            __builtin_amdgcn_global_load_lds((gfloat*)(vp + j * 256 + lane * 4),
                                             (lfloat*)&bV[j * 256], 16, 0, 0);
        }
    };

    auto compute = [&](int bufi, int p) {
        const float* bK = &sbuf[bufi][0];
        const float* bV = &sbuf[bufi][2048];
        const int tpage = t0 + p * BS_;
#pragma unroll
        for (int b = 0; b < 2; ++b) {
            float4 k4[4], v4[4];
#pragma unroll
            for (int i = 0; i < 4; ++i) {
                const int row = sub * 8 + b * 4 + i;
                k4[i] = *(const float4*)&bK[row * D_ + l32 * 4];
                v4[i] = *(const float4*)&bV[row * D_ + l32 * 4];
            }

            float sc[4][G_];
#pragma unroll
            for (int i = 0; i < 4; ++i)
#pragma unroll
                for (int g = 0; g < G_; ++g)
                    sc[i][g] = qv[g].x * k4[i].x + qv[g].y * k4[i].y +
                               qv[g].z * k4[i].z + qv[g].w * k4[i].w;

            // Butterfly reduce within the 32-lane group.
#pragma unroll
            for (int off = 16; off; off >>= 1)
#pragma unroll
                for (int i = 0; i < 4; ++i)
#pragma unroll
                    for (int g = 0; g < G_; ++g)
                        sc[i][g] += __shfl_xor(sc[i][g], off, 32);

            // Scale + mask tokens beyond len.
#pragma unroll
            for (int i = 0; i < 4; ++i) {
                const bool valid = (tpage + sub * 8 + b * 4 + i) < len;
#pragma unroll
                for (int g = 0; g < G_; ++g)
                    sc[i][g] = valid ? sc[i][g] * SCALE_ : -INFINITY;
            }

            // Online-softmax update (m finite always; masked p -> 0).
#pragma unroll
            for (int g = 0; g < G_; ++g) {
                const float smax = fmaxf(fmaxf(sc[0][g], sc[1][g]),
                                         fmaxf(sc[2][g], sc[3][g]));
                const float mn   = fmaxf(m[g], smax);
                const float corr = __expf(m[g] - mn);
                const float p0 = __expf(sc[0][g] - mn);
                const float p1 = __expf(sc[1][g] - mn);
                const float p2 = __expf(sc[2][g] - mn);
                const float p3 = __expf(sc[3][g] - mn);
                l[g] = l[g] * corr + ((p0 + p1) + (p2 + p3));
                acc[g].x = acc[g].x * corr + p0 * v4[0].x + p1 * v4[1].x + p2 * v4[2].x + p3 * v4[3].x;
                acc[g].y = acc[g].y * corr + p0 * v4[0].y + p1 * v4[1].y + p2 * v4[2].y + p3 * v4[3].y;
                acc[g].z = acc[g].z * corr + p0 * v4[0].z + p1 * v4[1].z + p2 * v4[2].z + p3 * v4[3].z;
                acc[g].w = acc[g].w * corr + p0 * v4[0].w + p1 * v4[1].w + p2 * v4[2].w + p3 * v4[3].w;
                m[g] = mn;
            }
        }
    };

    // Pipelined page loop: unrolled, compile-time buffer parity and bids
    // index; counted vmcnt (16 = next page's loads still in flight).
    stage(0, bids[0]);
#pragma unroll
    for (int p = 0; p < NPG_; ++p) {
        if (p >= np) break;                      // wave-uniform
        if (p + 1 < np) {
            stage((p + 1) & 1, bids[p + 1]);
            asm volatile("s_waitcnt vmcnt(16)" ::: "memory");
        } else {
            asm volatile("s_waitcnt vmcnt(0)" ::: "memory");
        }
        __builtin_amdgcn_sched_barrier(0);
        compute(p & 1, p);
    }

    // Merge the two 32-lane groups (partner = lane^32); group 0 writes.
    // ws layout: [S_][KVH_][MAXP_][G_][130] floats (17.04 MB, proven size).
#pragma unroll
    for (int g = 0; g < G_; ++g) {
        const float mo = __shfl_xor(m[g], 32, 64);
        const float lo = __shfl_xor(l[g], 32, 64);
        const float ox = __shfl_xor(acc[g].x, 32, 64);
        const float oy = __shfl_xor(acc[g].y, 32, 64);
        const float oz = __shfl_xor(acc[g].z, 32, 64);
        const float ow = __shfl_xor(acc[g].w, 32, 64);
        const float M  = fmaxf(m[g], mo);
        const float w  = __expf(m[g] - M);
        const float wo = __expf(mo - M);
        const float L  = w * l[g] + wo * lo;
        float4 A;
        A.x = w * acc[g].x + wo * ox;
        A.y = w * acc[g].y + wo * oy;
        A.z = w * acc[g].z + wo * oz;
        A.w = w * acc[g].w + wo * ow;
        if (sub == 0) {
            float* pb = ws + (((size_t)(s * KVH_ + kvh) * MAXP_ + part) * G_ + g) * 130;
            if (l32 == 0) { pb[0] = M; pb[1] = L; }
            *(float4*)(pb + 2 + l32 * 4) = A;
        }
    }
}

// Combine kernel: one WG (128 threads) per (seq, head); reduce over partitions.
__global__ __launch_bounds__(128)
void pa_combine(const float* __restrict__ ws,
                const int* __restrict__ cl,
                float* __restrict__ out)
{
    const int h = blockIdx.x;   // 0..31
    const int s = blockIdx.y;   // 0..63
    const int kvh = h >> 2;
    const int g   = h & 3;
    const int d   = threadIdx.x;

    const int len = cl[s];
    const int np  = (len + PART_ - 1) / PART_;

    const float* base = ws + (((size_t)(s * KVH_ + kvh) * MAXP_) * G_ + g) * 130;

    float M = MINIT_;
    for (int p = 0; p < np; ++p) M = fmaxf(M, base[(size_t)p * (G_ * 130)]);

    float L = 0.f, val = 0.f;
    for (int p = 0; p < np; ++p) {
        const float* pb = base + (size_t)p * (G_ * 130);
        const float w = __expf(pb[0] - M);
        L   += w * pb[1];
        val += w * pb[2 + d];
    }
    out[((size_t)s * H_ + h) * D_ + d] = val / L;
}

extern "C" void kernel_launch(void* const* d_in, const int* in_sizes, int n_in,
                              void* d_out, int out_size, void* d_ws, size_t ws_size,
                              hipStream_t stream)
{
    const float* q  = (const float*)d_in[0];
    const float* kc = (const float*)d_in[1];
    const float* vc = (const float*)d_in[2];
    const int*   bt = (const int*)d_in[3];
    const int*   cl = (const int*)d_in[4];
    float* out = (float*)d_out;
    float* ws  = (float*)d_ws;

    // ws layout: [S_][KVH_][MAXP_][G_][130] floats = 17.04 MB (proven fit).
    dim3 grid1(MAXP_, KVH_, S_);
    pa_partial<<<grid1, 64, 0, stream>>>(q, kc, vc, bt, cl, ws);

    dim3 grid2(H_, S_);
    pa_combine<<<grid2, 128, 0, stream>>>(ws, cl, out);
}